// Round 12
// baseline (268.914 us; speedup 1.0000x reference)
//
#include <hip/hip_runtime.h>

typedef unsigned short u16;
typedef unsigned int u32;
typedef unsigned long long u64;
typedef __attribute__((ext_vector_type(8))) short bf16x8;
typedef __attribute__((ext_vector_type(4))) short bf16x4;
typedef __attribute__((ext_vector_type(4))) float f32x4;
typedef __attribute__((ext_vector_type(2))) unsigned int u32x2;

#define AS1(p) ((const __attribute__((address_space(1))) void*)(p))
#define AS3(p) ((__attribute__((address_space(3))) void*)(p))

__device__ __forceinline__ u16 f2bf(float f) {   // RNE
    u32 u = __float_as_uint(f);
    u += 0x7fff + ((u >> 16) & 1);
    return (u16)(u >> 16);
}
// pack two floats to packed bf16x2 (round-half-up)
__device__ __forceinline__ u32 pack2bf(float lo, float hi) {
    u32 a = __float_as_uint(lo) + 0x8000u;
    u32 b = __float_as_uint(hi) + 0x8000u;
    return __builtin_amdgcn_perm(b, a, 0x07060302);   // {b[3],b[2],a[3],a[2]}
}
// single-instruction packed f32->bf16x2 (RNE) — no builtin on gfx950, asm per guide
__device__ __forceinline__ u32 cvtpk(float lo, float hi) {
    u32 r;
    asm("v_cvt_pk_bf16_f32 %0, %1, %2" : "=v"(r) : "v"(lo), "v"(hi));
    return r;
}

__device__ __forceinline__ void async16(const u16* g, u16* l) {
    __builtin_amdgcn_global_load_lds(AS1(g), AS3(l), 16, 0, 0);
}

// ---------------- fp32 -> bf16 conversion ----------------
__global__ __launch_bounds__(256) void cvt_kernel(const float* __restrict__ src,
                                                  u16* __restrict__ dst, int n) {
    int idx = (blockIdx.x * 256 + threadIdx.x) * 8;
    if (idx >= n) return;
    float4 a = *(const float4*)(src + idx);
    float4 b = *(const float4*)(src + idx + 4);
    uint4 o;
    o.x = (u32)f2bf(a.x) | ((u32)f2bf(a.y) << 16);
    o.y = (u32)f2bf(a.z) | ((u32)f2bf(a.w) << 16);
    o.z = (u32)f2bf(b.x) | ((u32)f2bf(b.y) << 16);
    o.w = (u32)f2bf(b.z) | ((u32)f2bf(b.w) << 16);
    *(uint4*)(dst + idx) = o;
}

__global__ __launch_bounds__(256) void cvt4_kernel(
    const float* __restrict__ s0, const float* __restrict__ s1,
    const float* __restrict__ s2, const float* __restrict__ s3,
    u16* __restrict__ d0, u16* __restrict__ d1,
    u16* __restrict__ d2, u16* __restrict__ d3) {
    const float* s; u16* d;
    switch (blockIdx.y) {
        case 0:  s = s0; d = d0; break;
        case 1:  s = s1; d = d1; break;
        case 2:  s = s2; d = d2; break;
        default: s = s3; d = d3; break;
    }
    int idx = (blockIdx.x * 256 + threadIdx.x) * 8;
    float4 a = *(const float4*)(s + idx);
    float4 b = *(const float4*)(s + idx + 4);
    uint4 o;
    o.x = (u32)f2bf(a.x) | ((u32)f2bf(a.y) << 16);
    o.y = (u32)f2bf(a.z) | ((u32)f2bf(a.w) << 16);
    o.z = (u32)f2bf(b.x) | ((u32)f2bf(b.y) << 16);
    o.w = (u32)f2bf(b.z) | ((u32)f2bf(b.w) << 16);
    *(uint4*)(d + idx) = o;
}

// ---------------- GEMM: C[m][o] = sum_k A[m][k]*W[o][k] + bias[o] ----------------
// R12: COUNTED-vmcnt 3-buffer BK=64 K-loop. R8's 2-buffer forced vmcnt(0)
// every interval (just-staged tile must land before the barrier). 3 buffers
// (96KB) need 1x512-thread block/CU — same 8 waves/CU TLP as 2x256. Tile
// still 128^2; wave owns 32m x 64n -> acc 32 VGPR (inside the no-spill box;
// R4/R6 spilled at acc>=128). Interval: stage(t+2) -> compute(t) -> vmcnt(4)
// -> barrier; stage=4 loads/thread so vmcnt(4) leaves exactly one stage in
// flight — drains to 0 only in the epilogue. Buffer overwritten by stage was
// last read two barriers ago.
// mode 0: z=0 -> Q bf16 (nh,s,d) pre-scaled by 0.125*log2e; z=1 -> K bf16;
//         z=2 -> V^T bf16 (nh,d,s). mode 1: fp32 row-major (m,o).
__global__ __launch_bounds__(512, 2) void gemm_bt(
    const u16* __restrict__ A,
    const u16* __restrict__ Wa, const u16* __restrict__ Wb, const u16* __restrict__ Wc,
    const float* __restrict__ ba, const float* __restrict__ bb, const float* __restrict__ bc,
    void* oa, void* ob_, void* oc, int mode)
{
    constexpr int K = 1024;
    __shared__ u16 smem[49152];   // 96KB: buf b at b*16384 (At 8192 + Wt 8192); epilogue reuses [0..16895]

    const int tid = threadIdx.x;
    const int lane = tid & 63, wv = tid >> 6;        // 8 waves
    const int l15 = lane & 15, quad = lane >> 4;
    const int wm = wv >> 1, wn = wv & 1;             // wave: 32 rows x 64 cols

    // XCD-aware swizzle (grid is 8 x 64 x z; dispatch order = linear L)
    const int L = blockIdx.x + (blockIdx.y << 3) + (blockIdx.z << 9);
    const int g = L & 7;          // XCD (assumes round-robin dispatch)
    const int j = L >> 3;
    const int z = j >> 6;         // 0..2 (or 0)
    const int r = j & 63;
    const int m0 = ((g << 3) + (r & 7)) * 128;   // y-chunk per XCD
    const int n0 = (r >> 3) * 128;

    const u16* W = (z == 0) ? Wa : ((z == 1) ? Wb : Wc);
    const float* bs = (z == 0) ? ba : ((z == 1) ? bb : bc);
    void* out = (z == 0) ? oa : ((z == 1) ? ob_ : oc);
    const bool swap_ = (mode == 1) || (z < 2);   // swapped: tile row = o, col = m

    f32x4 acc[2][4];
#pragma unroll
    for (int i = 0; i < 2; ++i)
#pragma unroll
        for (int j2 = 0; j2 < 4; ++j2) acc[i][j2] = (f32x4)0.f;

    // staging: tile = 128 rows x 64 k = 1024 chunks of 8 elems (16B) per matrix.
    // chunk c: row = c>>3, ch = c&7; global k-chunk stored = ch ^ (row&7).
    // 512 threads x 2 chunks each per matrix -> 4 async16 per thread per stage.
    const u16* AsP[2]; const u16* WsP[2]; int offC[2];
#pragma unroll
    for (int jj = 0; jj < 2; ++jj) {
        int c = jj * 512 + tid;              // 0..1023
        int row = c >> 3;
        int ko = ((c & 7) ^ (row & 7)) * 8;
        AsP[jj] = A + (size_t)(m0 + row) * K + ko;
        WsP[jj] = W + (size_t)(n0 + row) * K + ko;
        offC[jj] = c * 8;
    }

    auto stage = [&](u16* buf, int kk) {
        u16* At = buf;
        u16* Wt = buf + 8192;
#pragma unroll
        for (int jj = 0; jj < 2; ++jj) {
            async16(AsP[jj] + kk, At + offC[jj]);
            async16(WsP[jj] + kk, Wt + offC[jj]);
        }
    };
    auto compute = [&](const u16* buf) {
        const u16* At = buf;
        const u16* Wt = buf + 8192;
#pragma unroll
        for (int st = 0; st < 2; ++st) {
            bf16x8 af[2], wf[4];
#pragma unroll
            for (int t = 0; t < 2; ++t) {
                int rowa = wm * 32 + t * 16 + l15;
                af[t] = *(const bf16x8*)&At[rowa * 64 + (((st * 4 + quad) ^ (rowa & 7)) * 8)];
            }
#pragma unroll
            for (int t = 0; t < 4; ++t) {
                int rowb = wn * 64 + t * 16 + l15;
                wf[t] = *(const bf16x8*)&Wt[rowb * 64 + (((st * 4 + quad) ^ (rowb & 7)) * 8)];
            }
            __builtin_amdgcn_s_setprio(1);
            if (swap_) {
#pragma unroll
                for (int rt = 0; rt < 2; ++rt)
#pragma unroll
                    for (int ct = 0; ct < 4; ++ct)
                        acc[rt][ct] = __builtin_amdgcn_mfma_f32_16x16x32_bf16(wf[ct], af[rt], acc[rt][ct], 0, 0, 0);
            } else {
#pragma unroll
                for (int rt = 0; rt < 2; ++rt)
#pragma unroll
                    for (int ct = 0; ct < 4; ++ct)
                        acc[rt][ct] = __builtin_amdgcn_mfma_f32_16x16x32_bf16(af[rt], wf[ct], acc[rt][ct], 0, 0, 0);
            }
            __builtin_amdgcn_s_setprio(0);
        }
    };

#define W4 asm volatile("s_waitcnt vmcnt(4)" ::: "memory")
#define W0 asm volatile("s_waitcnt vmcnt(0)" ::: "memory")
#define BAR __builtin_amdgcn_s_barrier()

    u16* pc = smem;             // compute buffer (tile t)
    u16* pn = smem + 16384;     // next (tile t+1, staged & confirmed)
    u16* ps = smem + 32768;     // staging target (tile t+2)

    // prologue: tiles 0,1 in flight; confirm tile 0
    stage(pc, 0);
    stage(pn, 64);
    W4; BAR;
    // intervals t = 0..13: stage tile t+2, compute tile t, confirm tile t+1
#pragma unroll 1
    for (int t = 0; t < 14; ++t) {
        stage(ps, 128 + t * 64);
        compute(pc);
        W4; BAR;
        u16* tmp = pc; pc = pn; pn = ps; ps = tmp;
    }
    compute(pc);        // tile 14
    W0; BAR;            // tile 15 loads land
    pc = pn;
    compute(pc);        // tile 15
#undef W4
#undef W0
#undef BAR

    if (mode == 1) {
        // swapped: row = o (quad*4+r), col = m (l15); float4 over o
#pragma unroll
        for (int rt = 0; rt < 2; ++rt)
#pragma unroll
            for (int ct = 0; ct < 4; ++ct) {
                int m_ = m0 + wm * 32 + rt * 16 + l15;
                int ob = n0 + wn * 64 + ct * 16 + quad * 4;
                float4 b4 = *(const float4*)&bs[ob];
                float4 v;
                v.x = acc[rt][ct][0] + b4.x;
                v.y = acc[rt][ct][1] + b4.y;
                v.z = acc[rt][ct][2] + b4.z;
                v.w = acc[rt][ct][3] + b4.w;
                *(float4*)((float*)out + (size_t)m_ * 1024 + ob) = v;
            }
        return;
    }

    __syncthreads();   // all waves done reading k-loop buffers before smem reuse

    const int n = m0 >> 11, s0 = m0 & 2047;
    if (z < 2) {
        // tile -> LDS T[m][o] (132 stride), then coalesced (nh,s,d) streams
        const float qs = (z == 0) ? 0.18033688011112042f : 1.0f;  // 0.125*log2(e)
#pragma unroll
        for (int rt = 0; rt < 2; ++rt)
#pragma unroll
            for (int ct = 0; ct < 4; ++ct) {
                int ml = wm * 32 + rt * 16 + l15;
                int ol = wn * 64 + ct * 16 + quad * 4;
                float4 b4 = *(const float4*)&bs[n0 + ol];
                float v0 = (acc[rt][ct][0] + b4.x) * qs;
                float v1 = (acc[rt][ct][1] + b4.y) * qs;
                float v2 = (acc[rt][ct][2] + b4.z) * qs;
                float v3 = (acc[rt][ct][3] + b4.w) * qs;
                u32x2 pv = { pack2bf(v0, v1), pack2bf(v2, v3) };
                *(u32x2*)&smem[ml * 132 + ol] = pv;
            }
        __syncthreads();
        const int h0 = n0 >> 6;
#pragma unroll
        for (int p = 0; p < 4; ++p) {
            int hh = p >> 1, mh = p & 1;
            int m = mh * 64 + (tid >> 3), d = (tid & 7) * 8;
            bf16x8 vv = *(const bf16x8*)&smem[m * 132 + hh * 64 + d];
            u16* dst = (u16*)out + ((size_t)((n * 16 + h0 + hh) * 2048 + s0 + m)) * 64 + d;
            *(bf16x8*)dst = vv;
        }
    } else {
        // V^T: tile -> LDS T[o][m], then coalesced (nh,d,s) rows
#pragma unroll
        for (int rt = 0; rt < 2; ++rt)
#pragma unroll
            for (int ct = 0; ct < 4; ++ct) {
                int ol = wn * 64 + ct * 16 + l15;
                int ml = wm * 32 + rt * 16 + quad * 4;
                float b = bs[n0 + ol];
                float v0 = acc[rt][ct][0] + b;
                float v1 = acc[rt][ct][1] + b;
                float v2 = acc[rt][ct][2] + b;
                float v3 = acc[rt][ct][3] + b;
                u32x2 pv = { pack2bf(v0, v1), pack2bf(v2, v3) };
                *(u32x2*)&smem[ol * 132 + ml] = pv;
            }
        __syncthreads();
#pragma unroll
        for (int p = 0; p < 4; ++p) {
            int o = p * 32 + (tid >> 4), ms = (tid & 15) * 8;
            bf16x8 vv = *(const bf16x8*)&smem[o * 132 + ms];
            int og = n0 + o;
            int h = og >> 6, d = og & 63;
            u16* dst = (u16*)out + ((size_t)((n * 16 + h) * 64 + d)) * 2048 + s0 + ms;
            *(bf16x8*)dst = vv;
        }
    }
}

// ---------------- flash attention ----------------
// Q bf16 (nh,s,d) PRE-SCALED by 0.125*log2e; K bf16 (nh,s,d); VT bf16 (nh,d,s).
// S^T = K.Q^T; fixed-max softmax (scores bounded: exp2 sums < 2^20, fp32-safe).
// R11 (verified 84.5us dispatch, MfmaUtil 35): intra-tile dovetail at jt/kt
// granularity, zero register growth (VGPR 116, no scratch):
//   QK(0),QK(1) -> sm(0)||QK(2) -> sm(1)||QK(3) -> sm(2) -> pb(0) ->
//   PV(0)||sm(3) -> pb(1) -> stage -> PV(1)
__global__ __launch_bounds__(256, 2) void attn_kernel(
    const u16* __restrict__ Q, const u16* __restrict__ K_,
    const u16* __restrict__ VT, const int* __restrict__ mask,
    u16* __restrict__ Y)
{
    constexpr int S = 2048, DK = 64, STR = 72;
    __shared__ u16 Kt[2][64 * STR];
    __shared__ u16 Vt[2][64 * STR];

    const int tid = threadIdx.x;
    const int lane = tid & 63, w = tid >> 6;
    const int l15 = lane & 15, quad = lane >> 4;

    const int L = blockIdx.x + (blockIdx.y << 3);
    const int vb = (L & 7) * 64 + (L >> 3);
    const int nh = vb >> 3;
    const int n = nh >> 4, h = nh & 15;
    const int qbase = (vb & 7) * 256;

    const u16* Qh = Q + (size_t)nh * S * DK;
    const u16* Kh = K_ + (size_t)nh * S * DK;
    const u16* Vh = VT + (size_t)nh * DK * S;   // row d, stride S

    bf16x8 qf[4][2];
#pragma unroll
    for (int nt = 0; nt < 4; ++nt)
#pragma unroll
        for (int st = 0; st < 2; ++st)
            qf[nt][st] = *(const bf16x8*)(Qh + (size_t)(qbase + w * 64 + nt * 16 + l15) * DK + st * 32 + quad * 8);

    f32x4 o[4][4];   // [dt][nt]
#pragma unroll
    for (int dt = 0; dt < 4; ++dt)
#pragma unroll
        for (int nt = 0; nt < 4; ++nt) o[dt][nt] = (f32x4)0.f;
    float lsum[4] = {0.f, 0.f, 0.f, 0.f};

    const int r0 = tid >> 3, c8 = (tid & 7) * 8;

    // per-tile "fully unmasked" bitmap (one ballot per tile, once)
    u32 bm = 0;
    for (int t = 0; t < 32; ++t) {
        int mv = mask[n * S + t * 64 + lane];
        if (__ballot(mv != 0) == ~0ull) bm |= (1u << t);
    }

    // prologue: tile 0 -> buf 0
    {
        bf16x8 k0 = *(const bf16x8*)(Kh + (size_t)r0 * 64 + c8);
        bf16x8 k1 = *(const bf16x8*)(Kh + (size_t)(r0 + 32) * 64 + c8);
        bf16x8 v0 = *(const bf16x8*)(Vh + (size_t)r0 * S + c8);
        bf16x8 v1 = *(const bf16x8*)(Vh + (size_t)(r0 + 32) * S + c8);
        *(bf16x8*)&Kt[0][r0 * STR + c8] = k0;
        *(bf16x8*)&Kt[0][(r0 + 32) * STR + c8] = k1;
        *(bf16x8*)&Vt[0][r0 * STR + c8] = v0;
        *(bf16x8*)&Vt[0][(r0 + 32) * STR + c8] = v1;
    }
    __syncthreads();

    const f32x4 zf = (f32x4)0.f;

#define QK_JT(jt) do {                                                                       \
    bf16x8 kf0_ = *(const bf16x8*)&Ktc[((jt) * 16 + l15) * STR + quad * 8];                  \
    bf16x8 kf1_ = *(const bf16x8*)&Ktc[((jt) * 16 + l15) * STR + 32 + quad * 8];             \
    _Pragma("unroll")                                                                        \
    for (int nt = 0; nt < 4; ++nt) {                                                         \
        sacc[jt][nt] = __builtin_amdgcn_mfma_f32_16x16x32_bf16(kf0_, qf[nt][0], zf, 0, 0, 0);\
        sacc[jt][nt] = __builtin_amdgcn_mfma_f32_16x16x32_bf16(kf1_, qf[nt][1], sacc[jt][nt], 0, 0, 0);\
    }                                                                                        \
} while (0)

#define SM_JT(jt) do {                                                                       \
    if (!fast) {                                                                             \
        _Pragma("unroll")                                                                    \
        for (int rr = 0; rr < 4; ++rr) {                                                     \
            int mv_ = mask[n * S + it * 64 + (jt) * 16 + quad * 4 + rr];                     \
            _Pragma("unroll")                                                                \
            for (int nt = 0; nt < 4; ++nt)                                                   \
                if (mv_ == 0) sacc[jt][nt][rr] = -1e30f;                                     \
        }                                                                                    \
    }                                                                                        \
    _Pragma("unroll")                                                                        \
    for (int nt = 0; nt < 4; ++nt) {                                                         \
        float e0_ = __builtin_amdgcn_exp2f(sacc[jt][nt][0]);                                 \
        float e1_ = __builtin_amdgcn_exp2f(sacc[jt][nt][1]);                                 \
        float e2_ = __builtin_amdgcn_exp2f(sacc[jt][nt][2]);                                 \
        float e3_ = __builtin_amdgcn_exp2f(sacc[jt][nt][3]);                                 \
        ps[nt] += (e0_ + e1_) + (e2_ + e3_);                                                 \
        pkx[nt][jt] = cvtpk(e0_, e1_);   /* k = 16jt+4sq+{0,1} */                            \
        pky[nt][jt] = cvtpk(e2_, e3_);   /* k = 16jt+4sq+{2,3} */                            \
    }                                                                                        \
} while (0)

#define PB_KT(kt) do {                                                                       \
    _Pragma("unroll")                                                                        \
    for (int nt = 0; nt < 4; ++nt) {                                                         \
        auto rX_ = __builtin_amdgcn_permlane32_swap(pkx[nt][2 * (kt)], pkx[nt][2 * (kt) + 1], false, false);\
        auto rY_ = __builtin_amdgcn_permlane32_swap(pky[nt][2 * (kt)], pky[nt][2 * (kt) + 1], false, false);\
        auto sX_ = __builtin_amdgcn_permlane16_swap(rX_[0], rX_[1], false, false);           \
        auto sY_ = __builtin_amdgcn_permlane16_swap(rY_[0], rY_[1], false, false);           \
        union { u32 u[4]; bf16x8 v; } pu_;                                                   \
        pu_.u[0] = sX_[0];   /* k = 32kt+8qd+{0,1} */                                        \
        pu_.u[1] = sY_[0];   /* +{2,3} */                                                    \
        pu_.u[2] = sX_[1];   /* +{4,5} */                                                    \
        pu_.u[3] = sY_[1];   /* +{6,7} */                                                    \
        pb[nt] = pu_.v;                                                                      \
    }                                                                                        \
} while (0)

#define PV_KT(kt) do {                                                                       \
    _Pragma("unroll")                                                                        \
    for (int dt = 0; dt < 4; ++dt) {                                                         \
        bf16x8 vf_ = *(const bf16x8*)&Vtc[(dt * 16 + l15) * STR + (kt) * 32 + quad * 8];     \
        _Pragma("unroll")                                                                    \
        for (int nt = 0; nt < 4; ++nt)                                                       \
            o[dt][nt] = __builtin_amdgcn_mfma_f32_16x16x32_bf16(vf_, pb[nt], o[dt][nt], 0, 0, 0);\
    }                                                                                        \
} while (0)

#pragma unroll 1
    for (int it = 0; it < 32; ++it) {
        const int cur = it & 1, nxt = cur ^ 1;
        const u16* Ktc = &Kt[cur][0];
        const u16* Vtc = &Vt[cur][0];
        const bool fast = (bm >> it) & 1;

        // prefetch next tile into registers (latency hides under QK+softmax)
        const int kkn = ((it + 1) << 6) & (S - 1);
        bf16x8 rk0 = *(const bf16x8*)(Kh + (size_t)(kkn + r0) * 64 + c8);
        bf16x8 rk1 = *(const bf16x8*)(Kh + (size_t)(kkn + r0 + 32) * 64 + c8);
        bf16x8 rv0 = *(const bf16x8*)(Vh + (size_t)r0 * S + kkn + c8);
        bf16x8 rv1 = *(const bf16x8*)(Vh + (size_t)(r0 + 32) * S + kkn + c8);

        f32x4 sacc[4][4];           // [jt][nt]
        u32 pkx[4][4], pky[4][4];   // [nt][jt]
        float ps[4] = {0.f, 0.f, 0.f, 0.f};
        bf16x8 pb[4];               // one kt at a time; dies at its PV

        // ---- dovetailed schedule (scheduler interleaves MFMA & VALU streams) ----
        __builtin_amdgcn_s_setprio(1);
        QK_JT(0);
        QK_JT(1);
        SM_JT(0);          // overlaps QK(2) MFMAs
        QK_JT(2);
        SM_JT(1);          // overlaps QK(3)
        QK_JT(3);
        SM_JT(2);
        PB_KT(0);
        PV_KT(0);          // overlaps SM(3) VALU
        SM_JT(3);
        PB_KT(1);
        // stage next tile into buf[nxt] (ds_write drains under PV kt1)
        *(bf16x8*)&Kt[nxt][r0 * STR + c8] = rk0;
        *(bf16x8*)&Kt[nxt][(r0 + 32) * STR + c8] = rk1;
        *(bf16x8*)&Vt[nxt][r0 * STR + c8] = rv0;
        *(bf16x8*)&Vt[nxt][(r0 + 32) * STR + c8] = rv1;
        PV_KT(1);
        __builtin_amdgcn_s_setprio(0);

#pragma unroll
        for (int nt = 0; nt < 4; ++nt) lsum[nt] += ps[nt];

        __syncthreads();   // buf[nxt] published; everyone done reading buf[cur]
    }
#undef QK_JT
#undef SM_JT
#undef PB_KT
#undef PV_KT

    // ---- epilogue ----
#pragma unroll
    for (int nt = 0; nt < 4; ++nt) {
        float ls = lsum[nt];
        ls += __shfl_xor(ls, 16);
        ls += __shfl_xor(ls, 32);
        float rl = (ls > 0.f) ? 1.f / ls : 0.f;
        int qi = qbase + w * 64 + nt * 16 + l15;
#pragma unroll
        for (int dt = 0; dt < 4; ++dt) {
            u32x2 pv = { pack2bf(o[dt][nt][0] * rl, o[dt][nt][1] * rl),
                         pack2bf(o[dt][nt][2] * rl, o[dt][nt][3] * rl) };
            size_t base = ((size_t)(n * 2048 + qi)) * 1024 + h * 64 + dt * 16 + quad * 4;
            *(u32x2*)(Y + base) = pv;
        }
    }
}

// ---------------- host ----------------
extern "C" void kernel_launch(void* const* d_in, const int* in_sizes, int n_in,
                              void* d_out, int out_size, void* d_ws, size_t ws_size,
                              hipStream_t stream) {
    const float* x  = (const float*)d_in[0];
    const int* mask = (const int*)d_in[1];
    const float* Wq = (const float*)d_in[2];
    const float* bq = (const float*)d_in[3];
    const float* Wk = (const float*)d_in[4];
    const float* bk = (const float*)d_in[5];
    const float* Wv = (const float*)d_in[6];
    const float* bv = (const float*)d_in[7];
    const float* Wp = (const float*)d_in[8];
    const float* bp = (const float*)d_in[9];

    char* ws = (char*)d_ws;
    u16* xb  = (u16*)(ws);
    u16* wqb = (u16*)(ws + (16u << 20));
    u16* wkb = (u16*)(ws + (18u << 20));
    u16* wvb = (u16*)(ws + (20u << 20));
    u16* wpb = (u16*)(ws + (22u << 20));
    u16* Qb  = (u16*)(ws + (24u << 20));
    u16* Kb  = (u16*)(ws + (40u << 20));
    u16* Vb  = (u16*)(ws + (56u << 20));   // V^T (nh, d, s)
    u16* Yb  = (u16*)(ws + (72u << 20));

    cvt_kernel<<<4096, 256, 0, stream>>>(x, xb, 8388608);
    cvt4_kernel<<<dim3(512, 4), 256, 0, stream>>>(Wq, Wk, Wv, Wp, wqb, wkb, wvb, wpb);

    gemm_bt<<<dim3(8, 64, 3), 512, 0, stream>>>(xb, wqb, wkb, wvb, bq, bk, bv,
                                                (void*)Qb, (void*)Kb, (void*)Vb, 0);

    attn_kernel<<<dim3(8, 64), 256, 0, stream>>>(Qb, Kb, Vb, mask, Yb);

    gemm_bt<<<dim3(8, 64, 1), 512, 0, stream>>>(Yb, wpb, wpb, wpb, bp, bp, bp,
                                                d_out, d_out, d_out, 1);
}

// Round 13
// 257.309 us; speedup vs baseline: 1.0451x; 1.0451x over previous
//
#include <hip/hip_runtime.h>

typedef unsigned short u16;
typedef unsigned int u32;
typedef unsigned long long u64;
typedef __attribute__((ext_vector_type(8))) short bf16x8;
typedef __attribute__((ext_vector_type(4))) short bf16x4;
typedef __attribute__((ext_vector_type(4))) float f32x4;
typedef __attribute__((ext_vector_type(2))) unsigned int u32x2;

#define AS1(p) ((const __attribute__((address_space(1))) void*)(p))
#define AS3(p) ((__attribute__((address_space(3))) void*)(p))

__device__ __forceinline__ u16 f2bf(float f) {   // RNE
    u32 u = __float_as_uint(f);
    u += 0x7fff + ((u >> 16) & 1);
    return (u16)(u >> 16);
}
// pack two floats to packed bf16x2 (round-half-up)
__device__ __forceinline__ u32 pack2bf(float lo, float hi) {
    u32 a = __float_as_uint(lo) + 0x8000u;
    u32 b = __float_as_uint(hi) + 0x8000u;
    return __builtin_amdgcn_perm(b, a, 0x07060302);   // {b[3],b[2],a[3],a[2]}
}
// single-instruction packed f32->bf16x2 (RNE) — no builtin on gfx950, asm per guide
__device__ __forceinline__ u32 cvtpk(float lo, float hi) {
    u32 r;
    asm("v_cvt_pk_bf16_f32 %0, %1, %2" : "=v"(r) : "v"(lo), "v"(hi));
    return r;
}

__device__ __forceinline__ void async16(const u16* g, u16* l) {
    __builtin_amdgcn_global_load_lds(AS1(g), AS3(l), 16, 0, 0);
}

// ---------------- fp32 -> bf16 conversion (fused: x + 4 weights, one launch) ----------------
// y=0: x (8.4M elems, 4096 blocks x 2048). y=1: blocks 0..2047 cover the four
// 1M-elem weights (c>>9 selects weight, c&511 is its 512-block chunk); the
// rest return. Merging the two cvt launches removes one inter-kernel gap.
__global__ __launch_bounds__(256) void cvt_all(
    const float* __restrict__ x, u16* __restrict__ xb,
    const float* __restrict__ w0, const float* __restrict__ w1,
    const float* __restrict__ w2, const float* __restrict__ w3,
    u16* __restrict__ d0, u16* __restrict__ d1,
    u16* __restrict__ d2, u16* __restrict__ d3)
{
    const float* s; u16* d; int idx;
    if (blockIdx.y == 0) {
        s = x; d = xb;
        idx = (blockIdx.x * 256 + threadIdx.x) * 8;
    } else {
        int c = blockIdx.x;
        if (c >= 2048) return;
        switch (c >> 9) {
            case 0:  s = w0; d = d0; break;
            case 1:  s = w1; d = d1; break;
            case 2:  s = w2; d = d2; break;
            default: s = w3; d = d3; break;
        }
        idx = ((c & 511) * 256 + threadIdx.x) * 8;
    }
    float4 a = *(const float4*)(s + idx);
    float4 b = *(const float4*)(s + idx + 4);
    uint4 o;
    o.x = (u32)f2bf(a.x) | ((u32)f2bf(a.y) << 16);
    o.y = (u32)f2bf(a.z) | ((u32)f2bf(a.w) << 16);
    o.z = (u32)f2bf(b.x) | ((u32)f2bf(b.y) << 16);
    o.w = (u32)f2bf(b.z) | ((u32)f2bf(b.w) << 16);
    *(uint4*)(d + idx) = o;
}

// ---------------- GEMM: C[m][o] = sum_k A[m][k]*W[o][k] + bias[o] ----------------
// R8 structure (best-measured: non-attn 162us in R8's run): BK=64 2-buffer
// K-loop — 16 intervals of {stage 8 loads -> 32 MFMA + 16 ds_read -> vmcnt(0)
// -> barrier}. LDS 64KB, 2 blocks/CU. acc 64 VGPR is the only no-spill
// geometry at (256,2) (R4/R6 spilled with bigger acc). R12's 3-buffer
// 512-thread counted-vmcnt variant REVERTED: indistinguishable-to-worse
// within the +/-15us cross-container noise band (non-attn 185 vs 162 best).
// mode 0: z=0 -> Q bf16 (nh,s,d) pre-scaled by 0.125*log2e; z=1 -> K bf16;
//         z=2 -> V^T bf16 (nh,d,s). mode 1: fp32 row-major (m,o).
__global__ __launch_bounds__(256, 2) void gemm_bt(
    const u16* __restrict__ A,
    const u16* __restrict__ Wa, const u16* __restrict__ Wb, const u16* __restrict__ Wc,
    const float* __restrict__ ba, const float* __restrict__ bb, const float* __restrict__ bc,
    void* oa, void* ob_, void* oc, int mode)
{
    constexpr int K = 1024;
    __shared__ u16 smem[32768];   // 64KB: buf b at b*16384 (At 8192 + Wt 8192); epilogue reuses [0..16895]

    const int tid = threadIdx.x;
    const int lane = tid & 63, wv = tid >> 6;
    const int l15 = lane & 15, quad = lane >> 4;
    const int wr = wv >> 1, wc = wv & 1;

    // XCD-aware swizzle (grid is 8 x 64 x z; dispatch order = linear L)
    const int L = blockIdx.x + (blockIdx.y << 3) + (blockIdx.z << 9);
    const int g = L & 7;          // XCD (assumes round-robin dispatch)
    const int j = L >> 3;
    const int z = j >> 6;         // 0..2 (or 0)
    const int r = j & 63;
    const int m0 = ((g << 3) + (r & 7)) * 128;   // y-chunk per XCD
    const int n0 = (r >> 3) * 128;

    const u16* W = (z == 0) ? Wa : ((z == 1) ? Wb : Wc);
    const float* bs = (z == 0) ? ba : ((z == 1) ? bb : bc);
    void* out = (z == 0) ? oa : ((z == 1) ? ob_ : oc);
    const bool swap_ = (mode == 1) || (z < 2);   // swapped: tile row = o, col = m

    f32x4 acc[4][4];
#pragma unroll
    for (int i = 0; i < 4; ++i)
#pragma unroll
        for (int j2 = 0; j2 < 4; ++j2) acc[i][j2] = (f32x4)0.f;

    // staging geometry: tile = 128 rows x 64 k = 1024 chunks of 8 elems (16B).
    // chunk c: row = c>>3, ch = c&7; global k-chunk stored = ch ^ (row&7).
    const u16* AsP[4]; const u16* WsP[4]; int offC[4];
#pragma unroll
    for (int jj = 0; jj < 4; ++jj) {
        int c = (wv * 4 + jj) * 64 + lane;   // 0..1023
        int row = c >> 3;
        int ko = ((c & 7) ^ (row & 7)) * 8;
        AsP[jj] = A + (size_t)(m0 + row) * K + ko;
        WsP[jj] = W + (size_t)(n0 + row) * K + ko;
        offC[jj] = c * 8;
    }

    auto stage = [&](u16* buf, int kk) {
        u16* At = buf;
        u16* Wt = buf + 8192;
#pragma unroll
        for (int jj = 0; jj < 4; ++jj) async16(AsP[jj] + kk, At + offC[jj]);
#pragma unroll
        for (int jj = 0; jj < 4; ++jj) async16(WsP[jj] + kk, Wt + offC[jj]);
    };
    auto compute = [&](const u16* buf) {
        const u16* At = buf;
        const u16* Wt = buf + 8192;
#pragma unroll
        for (int st = 0; st < 2; ++st) {
            bf16x8 af[4], wf[4];
#pragma unroll
            for (int t = 0; t < 4; ++t) {
                int rowa = wr * 64 + t * 16 + l15;
                af[t] = *(const bf16x8*)&At[rowa * 64 + (((st * 4 + quad) ^ (rowa & 7)) * 8)];
                int rowb = wc * 64 + t * 16 + l15;
                wf[t] = *(const bf16x8*)&Wt[rowb * 64 + (((st * 4 + quad) ^ (rowb & 7)) * 8)];
            }
            __builtin_amdgcn_s_setprio(1);
            if (swap_) {
#pragma unroll
                for (int rt = 0; rt < 4; ++rt)
#pragma unroll
                    for (int ct = 0; ct < 4; ++ct)
                        acc[rt][ct] = __builtin_amdgcn_mfma_f32_16x16x32_bf16(wf[ct], af[rt], acc[rt][ct], 0, 0, 0);
            } else {
#pragma unroll
                for (int rt = 0; rt < 4; ++rt)
#pragma unroll
                    for (int ct = 0; ct < 4; ++ct)
                        acc[rt][ct] = __builtin_amdgcn_mfma_f32_16x16x32_bf16(af[rt], wf[ct], acc[rt][ct], 0, 0, 0);
            }
            __builtin_amdgcn_s_setprio(0);
        }
    };

    u16* const B0 = smem;
    u16* const B1 = smem + 16384;
#define W0 asm volatile("s_waitcnt vmcnt(0)" ::: "memory")
#define BAR __builtin_amdgcn_s_barrier()

    stage(B0, 0);
    W0; BAR;
#pragma unroll 1
    for (int kk = 0; kk < K - 128; kk += 128) {
        stage(B1, kk + 64);  compute(B0); W0; BAR;
        stage(B0, kk + 128); compute(B1); W0; BAR;
    }
    stage(B1, 960); compute(B0); W0; BAR;   // tile @896
    compute(B1);                            // tile @960
#undef W0
#undef BAR

    if (mode == 1) {
        // swapped: row = o (quad*4+r), col = m (l15); float4 over o; quad lanes
        // complete each 64B segment — near-full write efficiency
#pragma unroll
        for (int rt = 0; rt < 4; ++rt)
#pragma unroll
            for (int ct = 0; ct < 4; ++ct) {
                int m_ = m0 + wr * 64 + rt * 16 + l15;
                int ob = n0 + wc * 64 + ct * 16 + quad * 4;
                float4 b4 = *(const float4*)&bs[ob];
                float4 v;
                v.x = acc[rt][ct][0] + b4.x;
                v.y = acc[rt][ct][1] + b4.y;
                v.z = acc[rt][ct][2] + b4.z;
                v.w = acc[rt][ct][3] + b4.w;
                *(float4*)((float*)out + (size_t)m_ * 1024 + ob) = v;
            }
        return;
    }

    __syncthreads();   // all waves done reading k-loop buffers before smem reuse

    const int n = m0 >> 11, s0 = m0 & 2047;
    if (z < 2) {
        // tile -> LDS T[m][o] (132 stride), then coalesced (nh,s,d) streams
        const float qs = (z == 0) ? 0.18033688011112042f : 1.0f;  // 0.125*log2(e)
#pragma unroll
        for (int rt = 0; rt < 4; ++rt)
#pragma unroll
            for (int ct = 0; ct < 4; ++ct) {
                int ml = wr * 64 + rt * 16 + l15;
                int ol = wc * 64 + ct * 16 + quad * 4;
                float4 b4 = *(const float4*)&bs[n0 + ol];
                float v0 = (acc[rt][ct][0] + b4.x) * qs;
                float v1 = (acc[rt][ct][1] + b4.y) * qs;
                float v2 = (acc[rt][ct][2] + b4.z) * qs;
                float v3 = (acc[rt][ct][3] + b4.w) * qs;
                u32x2 pv = { pack2bf(v0, v1), pack2bf(v2, v3) };
                *(u32x2*)&smem[ml * 132 + ol] = pv;
            }
        __syncthreads();
        const int h0 = n0 >> 6;
#pragma unroll
        for (int p = 0; p < 8; ++p) {
            int hh = p >> 2, qq = p & 3;
            int m = qq * 32 + (tid >> 3), d = (tid & 7) * 8;
            bf16x8 vv = *(const bf16x8*)&smem[m * 132 + hh * 64 + d];
            u16* dst = (u16*)out + ((size_t)((n * 16 + h0 + hh) * 2048 + s0 + m)) * 64 + d;
            *(bf16x8*)dst = vv;
        }
    } else {
        // V^T: tile -> LDS T[o][m], then coalesced (nh,d,s) rows
#pragma unroll
        for (int rt = 0; rt < 4; ++rt)
#pragma unroll
            for (int ct = 0; ct < 4; ++ct) {
                int ol = wc * 64 + ct * 16 + l15;
                int ml = wr * 64 + rt * 16 + quad * 4;
                float b = bs[n0 + ol];
                float v0 = acc[rt][ct][0] + b;
                float v1 = acc[rt][ct][1] + b;
                float v2 = acc[rt][ct][2] + b;
                float v3 = acc[rt][ct][3] + b;
                u32x2 pv = { pack2bf(v0, v1), pack2bf(v2, v3) };
                *(u32x2*)&smem[ol * 132 + ml] = pv;
            }
        __syncthreads();
#pragma unroll
        for (int p = 0; p < 8; ++p) {
            int o = p * 16 + (tid >> 4), ms = (tid & 15) * 8;
            bf16x8 vv = *(const bf16x8*)&smem[o * 132 + ms];
            int og = n0 + o;
            int h = og >> 6, d = og & 63;
            u16* dst = (u16*)out + ((size_t)((n * 16 + h) * 64 + d)) * 2048 + s0 + ms;
            *(bf16x8*)dst = vv;
        }
    }
}

// ---------------- flash attention ----------------
// Q bf16 (nh,s,d) PRE-SCALED by 0.125*log2e; K bf16 (nh,s,d); VT bf16 (nh,d,s).
// S^T = K.Q^T; fixed-max softmax (scores bounded: exp2 sums < 2^20, fp32-safe).
// R11 (verified twice: 84.5/83.8us dispatch, MfmaUtil 34-35, VGPR 116, no
// scratch): intra-tile dovetail at jt/kt granularity:
//   QK(0),QK(1) -> sm(0)||QK(2) -> sm(1)||QK(3) -> sm(2) -> pb(0) ->
//   PV(0)||sm(3) -> pb(1) -> stage -> PV(1)
__global__ __launch_bounds__(256, 2) void attn_kernel(
    const u16* __restrict__ Q, const u16* __restrict__ K_,
    const u16* __restrict__ VT, const int* __restrict__ mask,
    u16* __restrict__ Y)
{
    constexpr int S = 2048, DK = 64, STR = 72;
    __shared__ u16 Kt[2][64 * STR];
    __shared__ u16 Vt[2][64 * STR];

    const int tid = threadIdx.x;
    const int lane = tid & 63, w = tid >> 6;
    const int l15 = lane & 15, quad = lane >> 4;

    const int L = blockIdx.x + (blockIdx.y << 3);
    const int vb = (L & 7) * 64 + (L >> 3);
    const int nh = vb >> 3;
    const int n = nh >> 4, h = nh & 15;
    const int qbase = (vb & 7) * 256;

    const u16* Qh = Q + (size_t)nh * S * DK;
    const u16* Kh = K_ + (size_t)nh * S * DK;
    const u16* Vh = VT + (size_t)nh * DK * S;   // row d, stride S

    bf16x8 qf[4][2];
#pragma unroll
    for (int nt = 0; nt < 4; ++nt)
#pragma unroll
        for (int st = 0; st < 2; ++st)
            qf[nt][st] = *(const bf16x8*)(Qh + (size_t)(qbase + w * 64 + nt * 16 + l15) * DK + st * 32 + quad * 8);

    f32x4 o[4][4];   // [dt][nt]
#pragma unroll
    for (int dt = 0; dt < 4; ++dt)
#pragma unroll
        for (int nt = 0; nt < 4; ++nt) o[dt][nt] = (f32x4)0.f;
    float lsum[4] = {0.f, 0.f, 0.f, 0.f};

    const int r0 = tid >> 3, c8 = (tid & 7) * 8;

    // per-tile "fully unmasked" bitmap (one ballot per tile, once)
    u32 bm = 0;
    for (int t = 0; t < 32; ++t) {
        int mv = mask[n * S + t * 64 + lane];
        if (__ballot(mv != 0) == ~0ull) bm |= (1u << t);
    }

    // prologue: tile 0 -> buf 0
    {
        bf16x8 k0 = *(const bf16x8*)(Kh + (size_t)r0 * 64 + c8);
        bf16x8 k1 = *(const bf16x8*)(Kh + (size_t)(r0 + 32) * 64 + c8);
        bf16x8 v0 = *(const bf16x8*)(Vh + (size_t)r0 * S + c8);
        bf16x8 v1 = *(const bf16x8*)(Vh + (size_t)(r0 + 32) * S + c8);
        *(bf16x8*)&Kt[0][r0 * STR + c8] = k0;
        *(bf16x8*)&Kt[0][(r0 + 32) * STR + c8] = k1;
        *(bf16x8*)&Vt[0][r0 * STR + c8] = v0;
        *(bf16x8*)&Vt[0][(r0 + 32) * STR + c8] = v1;
    }
    __syncthreads();

    const f32x4 zf = (f32x4)0.f;

#define QK_JT(jt) do {                                                                       \
    bf16x8 kf0_ = *(const bf16x8*)&Ktc[((jt) * 16 + l15) * STR + quad * 8];                  \
    bf16x8 kf1_ = *(const bf16x8*)&Ktc[((jt) * 16 + l15) * STR + 32 + quad * 8];             \
    _Pragma("unroll")                                                                        \
    for (int nt = 0; nt < 4; ++nt) {                                                         \
        sacc[jt][nt] = __builtin_amdgcn_mfma_f32_16x16x32_bf16(kf0_, qf[nt][0], zf, 0, 0, 0);\
        sacc[jt][nt] = __builtin_amdgcn_mfma_f32_16x16x32_bf16(kf1_, qf[nt][1], sacc[jt][nt], 0, 0, 0);\
    }                                                                                        \
} while (0)

#define SM_JT(jt) do {                                                                       \
    if (!fast) {                                                                             \
        _Pragma("unroll")                                                                    \
        for (int rr = 0; rr < 4; ++rr) {                                                     \
            int mv_ = mask[n * S + it * 64 + (jt) * 16 + quad * 4 + rr];                     \
            _Pragma("unroll")                                                                \
            for (int nt = 0; nt < 4; ++nt)                                                   \
                if (mv_ == 0) sacc[jt][nt][rr] = -1e30f;                                     \
        }                                                                                    \
    }                                                                                        \
    _Pragma("unroll")                                                                        \
    for (int nt = 0; nt < 4; ++nt) {                                                         \
        float e0_ = __builtin_amdgcn_exp2f(sacc[jt][nt][0]);                                 \
        float e1_ = __builtin_amdgcn_exp2f(sacc[jt][nt][1]);                                 \
        float e2_ = __builtin_amdgcn_exp2f(sacc[jt][nt][2]);                                 \
        float e3_ = __builtin_amdgcn_exp2f(sacc[jt][nt][3]);                                 \
        ps[nt] += (e0_ + e1_) + (e2_ + e3_);                                                 \
        pkx[nt][jt] = cvtpk(e0_, e1_);   /* k = 16jt+4sq+{0,1} */                            \
        pky[nt][jt] = cvtpk(e2_, e3_);   /* k = 16jt+4sq+{2,3} */                            \
    }                                                                                        \
} while (0)

#define PB_KT(kt) do {                                                                       \
    _Pragma("unroll")                                                                        \
    for (int nt = 0; nt < 4; ++nt) {                                                         \
        auto rX_ = __builtin_amdgcn_permlane32_swap(pkx[nt][2 * (kt)], pkx[nt][2 * (kt) + 1], false, false);\
        auto rY_ = __builtin_amdgcn_permlane32_swap(pky[nt][2 * (kt)], pky[nt][2 * (kt) + 1], false, false);\
        auto sX_ = __builtin_amdgcn_permlane16_swap(rX_[0], rX_[1], false, false);           \
        auto sY_ = __builtin_amdgcn_permlane16_swap(rY_[0], rY_[1], false, false);           \
        union { u32 u[4]; bf16x8 v; } pu_;                                                   \
        pu_.u[0] = sX_[0];   /* k = 32kt+8qd+{0,1} */                                        \
        pu_.u[1] = sY_[0];   /* +{2,3} */                                                    \
        pu_.u[2] = sX_[1];   /* +{4,5} */                                                    \
        pu_.u[3] = sY_[1];   /* +{6,7} */                                                    \
        pb[nt] = pu_.v;                                                                      \
    }                                                                                        \
} while (0)

#define PV_KT(kt) do {                                                                       \
    _Pragma("unroll")                                                                        \
    for (int dt = 0; dt < 4; ++dt) {                                                         \
        bf16x8 vf_ = *(const bf16x8*)&Vtc[(dt * 16 + l15) * STR + (kt) * 32 + quad * 8];     \
        _Pragma("unroll")                                                                    \
        for (int nt = 0; nt < 4; ++nt)                                                       \
            o[dt][nt] = __builtin_amdgcn_mfma_f32_16x16x32_bf16(vf_, pb[nt], o[dt][nt], 0, 0, 0);\
    }                                                                                        \
} while (0)

#pragma unroll 1
    for (int it = 0; it < 32; ++it) {
        const int cur = it & 1, nxt = cur ^ 1;
        const u16* Ktc = &Kt[cur][0];
        const u16* Vtc = &Vt[cur][0];
        const bool fast = (bm >> it) & 1;

        // prefetch next tile into registers (latency hides under QK+softmax)
        const int kkn = ((it + 1) << 6) & (S - 1);
        bf16x8 rk0 = *(const bf16x8*)(Kh + (size_t)(kkn + r0) * 64 + c8);
        bf16x8 rk1 = *(const bf16x8*)(Kh + (size_t)(kkn + r0 + 32) * 64 + c8);
        bf16x8 rv0 = *(const bf16x8*)(Vh + (size_t)r0 * S + kkn + c8);
        bf16x8 rv1 = *(const bf16x8*)(Vh + (size_t)(r0 + 32) * S + kkn + c8);

        f32x4 sacc[4][4];           // [jt][nt]
        u32 pkx[4][4], pky[4][4];   // [nt][jt]
        float ps[4] = {0.f, 0.f, 0.f, 0.f};
        bf16x8 pb[4];               // one kt at a time; dies at its PV

        // ---- dovetailed schedule (scheduler interleaves MFMA & VALU streams) ----
        __builtin_amdgcn_s_setprio(1);
        QK_JT(0);
        QK_JT(1);
        SM_JT(0);          // overlaps QK(2) MFMAs
        QK_JT(2);
        SM_JT(1);          // overlaps QK(3)
        QK_JT(3);
        SM_JT(2);
        PB_KT(0);
        PV_KT(0);          // overlaps SM(3) VALU
        SM_JT(3);
        PB_KT(1);
        // stage next tile into buf[nxt] (ds_write drains under PV kt1)
        *(bf16x8*)&Kt[nxt][r0 * STR + c8] = rk0;
        *(bf16x8*)&Kt[nxt][(r0 + 32) * STR + c8] = rk1;
        *(bf16x8*)&Vt[nxt][r0 * STR + c8] = rv0;
        *(bf16x8*)&Vt[nxt][(r0 + 32) * STR + c8] = rv1;
        PV_KT(1);
        __builtin_amdgcn_s_setprio(0);

#pragma unroll
        for (int nt = 0; nt < 4; ++nt) lsum[nt] += ps[nt];

        __syncthreads();   // buf[nxt] published; everyone done reading buf[cur]
    }
#undef QK_JT
#undef SM_JT
#undef PB_KT
#undef PV_KT

    // ---- epilogue ----
#pragma unroll
    for (int nt = 0; nt < 4; ++nt) {
        float ls = lsum[nt];
        ls += __shfl_xor(ls, 16);
        ls += __shfl_xor(ls, 32);
        float rl = (ls > 0.f) ? 1.f / ls : 0.f;
        int qi = qbase + w * 64 + nt * 16 + l15;
#pragma unroll
        for (int dt = 0; dt < 4; ++dt) {
            u32x2 pv = { pack2bf(o[dt][nt][0] * rl, o[dt][nt][1] * rl),
                         pack2bf(o[dt][nt][2] * rl, o[dt][nt][3] * rl) };
            size_t base = ((size_t)(n * 2048 + qi)) * 1024 + h * 64 + dt * 16 + quad * 4;
            *(u32x2*)(Y + base) = pv;
        }
    }
}

// ---------------- host ----------------
extern "C" void kernel_launch(void* const* d_in, const int* in_sizes, int n_in,
                              void* d_out, int out_size, void* d_ws, size_t ws_size,
                              hipStream_t stream) {
    const float* x  = (const float*)d_in[0];
    const int* mask = (const int*)d_in[1];
    const float* Wq = (const float*)d_in[2];
    const float* bq = (const float*)d_in[3];
    const float* Wk = (const float*)d_in[4];
    const float* bk = (const float*)d_in[5];
    const float* Wv = (const float*)d_in[6];
    const float* bv = (const float*)d_in[7];
    const float* Wp = (const float*)d_in[8];
    const float* bp = (const float*)d_in[9];

    char* ws = (char*)d_ws;
    u16* xb  = (u16*)(ws);
    u16* wqb = (u16*)(ws + (16u << 20));
    u16* wkb = (u16*)(ws + (18u << 20));
    u16* wvb = (u16*)(ws + (20u << 20));
    u16* wpb = (u16*)(ws + (22u << 20));
    u16* Qb  = (u16*)(ws + (24u << 20));
    u16* Kb  = (u16*)(ws + (40u << 20));
    u16* Vb  = (u16*)(ws + (56u << 20));   // V^T (nh, d, s)
    u16* Yb  = (u16*)(ws + (72u << 20));

    cvt_all<<<dim3(4096, 2), 256, 0, stream>>>(x, xb, Wq, Wk, Wv, Wp,
                                               wqb, wkb, wvb, wpb);

    gemm_bt<<<dim3(8, 64, 3), 256, 0, stream>>>(xb, wqb, wkb, wvb, bq, bk, bv,
                                                (void*)Qb, (void*)Kb, (void*)Vb, 0);

    attn_kernel<<<dim3(8, 64), 256, 0, stream>>>(Qb, Kb, Vb, mask, Yb);

    gemm_bt<<<dim3(8, 64, 1), 256, 0, stream>>>(Yb, wpb, wpb, wpb, bp, bp, bp,
                                                d_out, d_out, d_out, 1);
}